// Round 11
// baseline (756.279 us; speedup 1.0000x reference)
//
#include <hip/hip_runtime.h>
#include <hip/hip_bf16.h>

#define DD 256      // feature dim
#define NM 64       // memory slots
#define RPB 32      // rows per block (main kernel)
#define NTHR 256    // 4 waves

typedef unsigned long long u64;

// ---------------------------------------------------------------------------
// prep_tr: wt[d][o] = W[o][d] for Wq and Wk (read-coalesced, scatter-write)
// ---------------------------------------------------------------------------
__global__ __launch_bounds__(256) void prep_tr(
    const float* __restrict__ Wq,    // [DD][DD]
    const float* __restrict__ Wk,    // [DD][DD]
    float* __restrict__ wqt,         // out [DD][DD]
    float* __restrict__ wkt)         // out [DD][DD]
{
    const int o = blockIdx.x;    // source row
    const int d = threadIdx.x;   // source col (coalesced read)
    if (blockIdx.y == 0) wqt[d * DD + o] = Wq[o * DD + d];
    else                 wkt[d * DD + o] = Wk[o * DD + d];
}

// ---------------------------------------------------------------------------
// prep_kT: kT4[(o>>2)*(NM*4) + n*4 + (o&3)] = k[n][o]
//          k[n][o] = sum_d mem[n][d]*Wk[o][d]  (fp32, d-ascending single-acc)
//          bias[n] = fl32(max(log(imp*0.99^age), -10))
// ---------------------------------------------------------------------------
__global__ __launch_bounds__(256) void prep_kT(
    const float* __restrict__ mem,   // [NM][DD]
    const float* __restrict__ wkt,   // [DD][DD]  (WkT: wkt[d][o])
    const float* __restrict__ imp,   // [NM]
    const float* __restrict__ age,   // [NM]
    float* __restrict__ kT4,         // out [DD/4][NM][4]
    float* __restrict__ bias)        // out [NM]
{
    const int n = blockIdx.x;   // memory slot
    const int o = threadIdx.x;  // output feature
    const float* mrow = mem + n * DD;     // uniform
    float acc = 0.f;
    for (int d = 0; d < DD; ++d)
        acc = fmaf(mrow[d], wkt[d * DD + o], acc);   // coalesced in o
    kT4[(o >> 2) * (NM * 4) + n * 4 + (o & 3)] = acc;

    if (o == 0) {
        double eff = (double)imp[n] * pow(0.99, (double)age[n]);
        float b = (float)log(eff);
        if (!(b >= -10.0f)) b = -10.0f;   // catches -inf/NaN too
        bias[n] = b;
    }
}

// ---------------------------------------------------------------------------
// fused main: 32 rows/block, 256 threads (4 waves), 32 KB LDS.
// __launch_bounds__(256,2): VGPR cap 256 -> compiler's natural ~104 regs,
// NO spill (R8/R10 lesson: tighter caps squeeze to 64 VGPR + scratch spill:
// +55 MB write, +28 MB read traffic). Resource math: VGPR 104 -> 4 waves/
// SIMD; LDS 32KB -> 5 blocks/CU; net 4 blocks/CU = 16 waves/CU (~50% occ),
// 2x R9's 8 waves/CU (R6/R10 evidence: small blocks co-schedule).
//  A: q = query @ Wq^T  (wave w: rows 8w..8w+7; lane l: o=4l..4l+3;
//     chain per (row,o): d-ascending single-acc fmaf — bit-identical to R10)
//  B: s = q @ kT        (lane -> row l&31, n-group 2w+(l>>5); kT uniform
//     s_load per half-wave; chain o-ascending — bit-identical)
//  After barrier, q_lds dead: scores + sel arrays ALIAS into q_lds.
//  2: per-row top-k: wave w lanes 0..7 -> rows 8w..8w+7.
//  3: attn + retrieved stores (PV chain rank-ascending — bit-identical).
// q_lds swizzle: row lr, o-slot p at p^lr. s rows: col c at (c+r)&63.
// ---------------------------------------------------------------------------
__global__ __launch_bounds__(NTHR, 2) void mb_fused(
    const float* __restrict__ query,   // [M][DD]
    const float* __restrict__ mem,     // [NM][DD]
    const float4* __restrict__ wqt4,   // [DD][NM]: wqt4[d*64+l] = WqT[d][4l..4l+3]
    const float4* __restrict__ kT44,   // [DD/4][NM]: kT44[og*64+n] = k[n][4og..4og+3]
    const float* __restrict__ bias,    // [NM]
    const int* __restrict__ topk_p,
    float* __restrict__ out_ret,       // [M][DD]
    float* __restrict__ out_attn,      // [M][NM]
    int M)
{
    __shared__ float q_lds[RPB * DD];        // 32 KB; reused after Phase B:
    float* s_f   = q_lds;                    //   s[32][64] (+r col rotation)
    int*   sel_i = (int*)(q_lds + RPB * NM); //   [32][16]
    float* sel_w = q_lds + RPB * NM + RPB * 16;

    const int t = threadIdx.x;
    const int l = t & 63;
    const int w = __builtin_amdgcn_readfirstlane((int)(t >> 6));  // 0..3
    const int row0 = blockIdx.x * RPB;
    const int k = *topk_p;

    // ================= Phase A: q-GEMM =================
    {
        const float* qb[8];
#pragma unroll
        for (int rr = 0; rr < 8; ++rr) {
            int r = row0 + w * 8 + rr;
            if (r > M - 1) r = M - 1;
            qb[rr] = query + (size_t)r * DD;   // wave-uniform
        }

        float a0[8], a1[8], a2[8], a3[8];      // a{c}[rr]: o = 4l + c
#pragma unroll
        for (int rr = 0; rr < 8; ++rr) { a0[rr] = 0.f; a1[rr] = 0.f; a2[rr] = 0.f; a3[rr] = 0.f; }

        for (int d0 = 0; d0 < DD; d0 += 4) {
            const float4 w0 = wqt4[(d0 + 0) * NM + l];   // coalesced 1KB/instr
            const float4 w1 = wqt4[(d0 + 1) * NM + l];
            const float4 w2 = wqt4[(d0 + 2) * NM + l];
            const float4 w3 = wqt4[(d0 + 3) * NM + l];
#pragma unroll
            for (int rr = 0; rr < 8; ++rr) {
                const float4 qq = *reinterpret_cast<const float4*>(qb[rr] + d0); // uniform
                float v0 = a0[rr], v1 = a1[rr], v2 = a2[rr], v3 = a3[rr];
                // d-ascending per chain (identical to R10)
                v0 = fmaf(qq.x, w0.x, v0); v0 = fmaf(qq.y, w1.x, v0);
                v0 = fmaf(qq.z, w2.x, v0); v0 = fmaf(qq.w, w3.x, v0);
                v1 = fmaf(qq.x, w0.y, v1); v1 = fmaf(qq.y, w1.y, v1);
                v1 = fmaf(qq.z, w2.y, v1); v1 = fmaf(qq.w, w3.y, v1);
                v2 = fmaf(qq.x, w0.z, v2); v2 = fmaf(qq.y, w1.z, v2);
                v2 = fmaf(qq.z, w2.z, v2); v2 = fmaf(qq.w, w3.z, v2);
                v3 = fmaf(qq.x, w0.w, v3); v3 = fmaf(qq.y, w1.w, v3);
                v3 = fmaf(qq.z, w2.w, v3); v3 = fmaf(qq.w, w3.w, v3);
                a0[rr] = v0; a1[rr] = v1; a2[rr] = v2; a3[rr] = v3;
            }
        }
#pragma unroll
        for (int rr = 0; rr < 8; ++rr) {
            const int lr = w * 8 + rr;        // 0..31
            float4 v; v.x = a0[rr]; v.y = a1[rr]; v.z = a2[rr]; v.w = a3[rr];
            *reinterpret_cast<float4*>(&q_lds[lr * DD + (((l ^ lr) & 63) << 2)]) = v;
        }
    }
    __syncthreads();

    // ================= Phase B: scores (registers only) =================
    // lane -> row r = l&31; n-group g = 2w + (l>>5); n in [8g, 8g+8)
    const int r_b = l & 31;
    const int nb  = (w * 2 + (l >> 5)) * 8;
    float sc[8];
    {
#pragma unroll
        for (int j = 0; j < 8; ++j) sc[j] = 0.f;

        for (int og = 0; og < DD / 4; ++og) {
            const float4 q4 = *reinterpret_cast<const float4*>(
                &q_lds[r_b * DD + (((og ^ r_b) & 63) << 2)]);
            const float4* ktp = kT44 + og * NM + nb;      // uniform per half-wave
#pragma unroll
            for (int j = 0; j < 8; ++j) {
                const float4 kt = ktp[j];
                float v = sc[j];
                v = fmaf(q4.x, kt.x, v);
                v = fmaf(q4.y, kt.y, v);
                v = fmaf(q4.z, kt.z, v);
                v = fmaf(q4.w, kt.w, v);
                sc[j] = v;
            }
        }
    }
    __syncthreads();    // all q_lds reads done -> q_lds storage reusable

    // ---- write scores into aliased s_f[32][64] (col c stored at (c+row)&63)
#pragma unroll
    for (int j = 0; j < 8; ++j)
        s_f[r_b * NM + ((nb + j + r_b) & 63)] = sc[j] * 0.0625f + bias[nb + j];
    __syncthreads();

    // ================= Phase 2: per-row top-k (wave w, lanes 0..7) =================
    if (l < 8) {
        const int r = w * 8 + l;              // 0..31
        float sv[NM];
#pragma unroll
        for (int n = 0; n < NM; ++n) sv[n] = s_f[r * NM + ((n + r) & 63)];

        if (k < NM) {
            const int kk = k < 16 ? k : 16;   // dataset: k = 8
            u64 taken = 0ull;
            float mmax = 0.f, Z = 0.f;
            for (int i = 0; i < kk; ++i) {
                float m = -1.0e30f;
                int idx = 0;
#pragma unroll
                for (int n = 0; n < NM; ++n) {
                    const bool avail  = ((taken >> n) & 1ull) == 0ull;
                    const bool better = avail && (sv[n] > m);  // strict >: lowest idx ties
                    m   = better ? sv[n] : m;
                    idx = better ? n : idx;
                }
                taken |= (1ull << idx);
                if (i == 0) mmax = m;
                const float wv = expf(m - mmax);
                Z += wv;
                sel_i[r * 16 + i] = idx;
                sel_w[r * 16 + i] = wv;       // raw; divided once Z final
            }
#pragma unroll
            for (int n = 0; n < NM; ++n) s_f[r * NM + ((n + r) & 63)] = 0.f;
            for (int i = 0; i < kk; ++i) {
                const float wz = sel_w[r * 16 + i] / Z;
                sel_w[r * 16 + i] = wz;
                s_f[r * NM + ((sel_i[r * 16 + i] + r) & 63)] = wz;
            }
        } else {
            // full-softmax fallback (top_k >= N)
            float m = -1.0e30f;
#pragma unroll
            for (int n = 0; n < NM; ++n) m = sv[n] > m ? sv[n] : m;
            float Z = 0.f;
#pragma unroll
            for (int n = 0; n < NM; ++n) Z += expf(sv[n] - m);
#pragma unroll
            for (int n = 0; n < NM; ++n) s_f[r * NM + ((n + r) & 63)] = expf(sv[n] - m) / Z;
        }
    }
    __syncthreads();

    // ================= Phase 3a: attn stores (coalesced) =================
#pragma unroll
    for (int it = 0; it < (RPB * NM) / NTHR; ++it) {   // 8 iters
        const int idx  = it * NTHR + t;
        const int r    = idx >> 6, n = idx & 63;       // r uniform per wave
        const int grow = row0 + r;
        if (grow < M) out_attn[(size_t)grow * NM + n] = s_f[r * NM + ((n + r) & 63)];
    }

    // ================= Phase 3b: retrieved (PV) =================
    // lanes = d (NTHR == DD); one row per iteration
    {
        const int kk = k < 16 ? k : 16;
        for (int r = 0; r < RPB; ++r) {
            const int grow = row0 + r;
            if (grow >= M) break;
            float a = 0.f;
            if (k < NM) {
                for (int i = 0; i < kk; ++i) {
                    const int   mi = sel_i[r * 16 + i];
                    const float wz = sel_w[r * 16 + i];
                    a = fmaf(wz, mem[(size_t)mi * DD + t], a);   // rank-ascending chain
                }
            } else {
                for (int n = 0; n < NM; ++n) {
                    const float wz = s_f[r * NM + ((n + r) & 63)];
                    a = fmaf(wz, mem[(size_t)n * DD + t], a);    // n-ascending
                }
            }
            out_ret[(size_t)grow * DD + t] = a;
        }
    }
}

// ---------------------------------------------------------------------------
extern "C" void kernel_launch(void* const* d_in, const int* in_sizes, int n_in,
                              void* d_out, int out_size, void* d_ws, size_t ws_size,
                              hipStream_t stream) {
    const float* query      = (const float*)d_in[0];
    const float* memory     = (const float*)d_in[1];
    const float* importance = (const float*)d_in[2];
    const float* age        = (const float*)d_in[3];
    const float* Wq         = (const float*)d_in[4];
    const float* Wk         = (const float*)d_in[5];
    const int*   topk       = (const int*)d_in[6];

    const int M = in_sizes[0] / DD;   // B*S = 131072

    float* kT4  = (float*)d_ws;                      // [DD/4][NM][4] = 64 KB
    float* bias = kT4 + (size_t)DD * NM;             // [NM]
    float* wqt  = bias + 64;                         // [DD][DD] = 256 KB (16B aligned)
    float* wkt  = wqt + (size_t)DD * DD;             // [DD][DD] = 256 KB

    hipLaunchKernelGGL(prep_tr, dim3(DD, 2), dim3(DD), 0, stream,
                       Wq, Wk, wqt, wkt);
    hipLaunchKernelGGL(prep_kT, dim3(NM), dim3(DD), 0, stream,
                       memory, wkt, importance, age, kT4, bias);

    float* out_ret  = (float*)d_out;
    float* out_attn = out_ret + (size_t)M * DD;

    hipLaunchKernelGGL(mb_fused, dim3((M + RPB - 1) / RPB), dim3(NTHR), 0, stream,
                       query, memory,
                       (const float4*)wqt, (const float4*)kT4,
                       bias, topk, out_ret, out_attn, M);
}

// Round 12
// 673.322 us; speedup vs baseline: 1.1232x; 1.1232x over previous
//
#include <hip/hip_runtime.h>
#include <hip/hip_bf16.h>

#define DD 256      // feature dim
#define NM 64       // memory slots
#define RPB 32      // rows per block (main kernel)
#define NTHR 256    // 4 waves

typedef unsigned long long u64;

// ---------------------------------------------------------------------------
// prep_tr: wt[d][o] = W[o][d] for Wq and Wk (read-coalesced, scatter-write)
// ---------------------------------------------------------------------------
__global__ __launch_bounds__(256) void prep_tr(
    const float* __restrict__ Wq,    // [DD][DD]
    const float* __restrict__ Wk,    // [DD][DD]
    float* __restrict__ wqt,         // out [DD][DD]
    float* __restrict__ wkt)         // out [DD][DD]
{
    const int o = blockIdx.x;    // source row
    const int d = threadIdx.x;   // source col (coalesced read)
    if (blockIdx.y == 0) wqt[d * DD + o] = Wq[o * DD + d];
    else                 wkt[d * DD + o] = Wk[o * DD + d];
}

// ---------------------------------------------------------------------------
// prep_kT: kT4[(o>>2)*(NM*4) + n*4 + (o&3)] = k[n][o]
//          k[n][o] = sum_d mem[n][d]*Wk[o][d]  (fp32, d-ascending single-acc)
//          bias[n] = fl32(max(log(imp*0.99^age), -10))
// ---------------------------------------------------------------------------
__global__ __launch_bounds__(256) void prep_kT(
    const float* __restrict__ mem,   // [NM][DD]
    const float* __restrict__ wkt,   // [DD][DD]  (WkT: wkt[d][o])
    const float* __restrict__ imp,   // [NM]
    const float* __restrict__ age,   // [NM]
    float* __restrict__ kT4,         // out [DD/4][NM][4]
    float* __restrict__ bias)        // out [NM]
{
    const int n = blockIdx.x;   // memory slot
    const int o = threadIdx.x;  // output feature
    const float* mrow = mem + n * DD;     // uniform
    float acc = 0.f;
    for (int d = 0; d < DD; ++d)
        acc = fmaf(mrow[d], wkt[d * DD + o], acc);   // coalesced in o
    kT4[(o >> 2) * (NM * 4) + n * 4 + (o & 3)] = acc;

    if (o == 0) {
        double eff = (double)imp[n] * pow(0.99, (double)age[n]);
        float b = (float)log(eff);
        if (!(b >= -10.0f)) b = -10.0f;   // catches -inf/NaN too
        bias[n] = b;
    }
}

// ---------------------------------------------------------------------------
// fused main: 32 rows/block, 256 threads (4 waves), 32 KB LDS.
// R12 changes vs R11 (all FMA chains bit-identical):
//  - Phase A: 1-deep register prefetch of wqt tiles (wrap-around index) to
//    hide VMEM latency under the 128-FMA body.
//  - Phase B: lanes 0..31 = rows, wave w owns n in [16w,16w+16) -> kT
//    address is WAVE-uniform again (s_load; R10/R11's half-wave split made
//    it 8 VMEM/iter — the regression vs R7). q4 ds_read prefetched 1 ahead.
//  - PV: float4 per lane (lane = d-quad), 4x fewer VMEM, coalesced stores.
// ---------------------------------------------------------------------------
__global__ __launch_bounds__(NTHR, 2) void mb_fused(
    const float* __restrict__ query,   // [M][DD]
    const float* __restrict__ mem,     // [NM][DD]
    const float4* __restrict__ wqt4,   // [DD][NM]: wqt4[d*64+l] = WqT[d][4l..4l+3]
    const float4* __restrict__ kT44,   // [DD/4][NM]: kT44[og*64+n] = k[n][4og..4og+3]
    const float* __restrict__ bias,    // [NM]
    const int* __restrict__ topk_p,
    float* __restrict__ out_ret,       // [M][DD]
    float* __restrict__ out_attn,      // [M][NM]
    int M)
{
    __shared__ float q_lds[RPB * DD];        // 32 KB; reused after Phase B:
    float* s_f   = q_lds;                    //   s[32][64] (+r col rotation)
    int*   sel_i = (int*)(q_lds + RPB * NM); //   [32][16]
    float* sel_w = q_lds + RPB * NM + RPB * 16;

    const int t = threadIdx.x;
    const int l = t & 63;
    const int w = __builtin_amdgcn_readfirstlane((int)(t >> 6));  // 0..3
    const int row0 = blockIdx.x * RPB;
    const int k = *topk_p;

    // ================= Phase A: q-GEMM (prefetched) =================
    {
        const float* qb[8];
#pragma unroll
        for (int rr = 0; rr < 8; ++rr) {
            int r = row0 + w * 8 + rr;
            if (r > M - 1) r = M - 1;
            qb[rr] = query + (size_t)r * DD;   // wave-uniform -> s_load
        }

        float a0[8], a1[8], a2[8], a3[8];      // a{c}[rr]: o = 4l + c
#pragma unroll
        for (int rr = 0; rr < 8; ++rr) { a0[rr] = 0.f; a1[rr] = 0.f; a2[rr] = 0.f; a3[rr] = 0.f; }

        // preload tile for d0 = 0
        float4 cw0 = wqt4[0 * NM + l];
        float4 cw1 = wqt4[1 * NM + l];
        float4 cw2 = wqt4[2 * NM + l];
        float4 cw3 = wqt4[3 * NM + l];

        for (int d0 = 0; d0 < DD; d0 += 4) {
            // prefetch next tile (wraps to 0 on last iter -- harmless reload)
            const int dn = (d0 + 4) & (DD - 1);
            const float4 nw0 = wqt4[(dn + 0) * NM + l];
            const float4 nw1 = wqt4[(dn + 1) * NM + l];
            const float4 nw2 = wqt4[(dn + 2) * NM + l];
            const float4 nw3 = wqt4[(dn + 3) * NM + l];
#pragma unroll
            for (int rr = 0; rr < 8; ++rr) {
                const float4 qq = *reinterpret_cast<const float4*>(qb[rr] + d0); // uniform
                float v0 = a0[rr], v1 = a1[rr], v2 = a2[rr], v3 = a3[rr];
                // d-ascending per chain (identical to R11)
                v0 = fmaf(qq.x, cw0.x, v0); v0 = fmaf(qq.y, cw1.x, v0);
                v0 = fmaf(qq.z, cw2.x, v0); v0 = fmaf(qq.w, cw3.x, v0);
                v1 = fmaf(qq.x, cw0.y, v1); v1 = fmaf(qq.y, cw1.y, v1);
                v1 = fmaf(qq.z, cw2.y, v1); v1 = fmaf(qq.w, cw3.y, v1);
                v2 = fmaf(qq.x, cw0.z, v2); v2 = fmaf(qq.y, cw1.z, v2);
                v2 = fmaf(qq.z, cw2.z, v2); v2 = fmaf(qq.w, cw3.z, v2);
                v3 = fmaf(qq.x, cw0.w, v3); v3 = fmaf(qq.y, cw1.w, v3);
                v3 = fmaf(qq.z, cw2.w, v3); v3 = fmaf(qq.w, cw3.w, v3);
                a0[rr] = v0; a1[rr] = v1; a2[rr] = v2; a3[rr] = v3;
            }
            cw0 = nw0; cw1 = nw1; cw2 = nw2; cw3 = nw3;
        }
#pragma unroll
        for (int rr = 0; rr < 8; ++rr) {
            const int lr = w * 8 + rr;        // 0..31
            float4 v; v.x = a0[rr]; v.y = a1[rr]; v.z = a2[rr]; v.w = a3[rr];
            *reinterpret_cast<float4*>(&q_lds[lr * DD + (((l ^ lr) & 63) << 2)]) = v;
        }
    }
    __syncthreads();

    // ================= Phase B: scores (registers only) =================
    // lanes 0..31: lane = row; wave w owns n in [16w, 16w+16) -> kT uniform
    const int r_b = l & 31;
    const int nb  = w * 16;
    float sc[16];
    if (l < 32) {
#pragma unroll
        for (int j = 0; j < 16; ++j) sc[j] = 0.f;

        float4 q4c = *reinterpret_cast<const float4*>(
            &q_lds[r_b * DD + (((0 ^ r_b) & 63) << 2)]);

        for (int og = 0; og < DD / 4; ++og) {
            const int ogn = (og + 1) & 63;    // wraps on last iter
            const float4 q4n = *reinterpret_cast<const float4*>(
                &q_lds[r_b * DD + (((ogn ^ r_b) & 63) << 2)]);
            const float4* ktp = kT44 + og * NM + nb;      // WAVE-uniform -> s_load
#pragma unroll
            for (int j = 0; j < 16; ++j) {
                const float4 kt = ktp[j];
                float v = sc[j];
                v = fmaf(q4c.x, kt.x, v);
                v = fmaf(q4c.y, kt.y, v);
                v = fmaf(q4c.z, kt.z, v);
                v = fmaf(q4c.w, kt.w, v);
                sc[j] = v;
            }
            q4c = q4n;
        }
    }
    __syncthreads();    // all q_lds reads done -> q_lds storage reusable

    // ---- write scores into aliased s_f[32][64] (col c stored at (c+row)&63)
    if (l < 32) {
#pragma unroll
        for (int j = 0; j < 16; ++j)
            s_f[r_b * NM + ((nb + j + r_b) & 63)] = sc[j] * 0.0625f + bias[nb + j];
    }
    __syncthreads();

    // ================= Phase 2: per-row top-k (wave w, lanes 0..7) =================
    if (l < 8) {
        const int r = w * 8 + l;              // 0..31
        float sv[NM];
#pragma unroll
        for (int n = 0; n < NM; ++n) sv[n] = s_f[r * NM + ((n + r) & 63)];

        if (k < NM) {
            const int kk = k < 16 ? k : 16;   // dataset: k = 8
            u64 taken = 0ull;
            float mmax = 0.f, Z = 0.f;
            for (int i = 0; i < kk; ++i) {
                float m = -1.0e30f;
                int idx = 0;
#pragma unroll
                for (int n = 0; n < NM; ++n) {
                    const bool avail  = ((taken >> n) & 1ull) == 0ull;
                    const bool better = avail && (sv[n] > m);  // strict >: lowest idx ties
                    m   = better ? sv[n] : m;
                    idx = better ? n : idx;
                }
                taken |= (1ull << idx);
                if (i == 0) mmax = m;
                const float wv = expf(m - mmax);
                Z += wv;
                sel_i[r * 16 + i] = idx;
                sel_w[r * 16 + i] = wv;       // raw; divided once Z final
            }
#pragma unroll
            for (int n = 0; n < NM; ++n) s_f[r * NM + ((n + r) & 63)] = 0.f;
            for (int i = 0; i < kk; ++i) {
                const float wz = sel_w[r * 16 + i] / Z;
                sel_w[r * 16 + i] = wz;
                s_f[r * NM + ((sel_i[r * 16 + i] + r) & 63)] = wz;
            }
        } else {
            // full-softmax fallback (top_k >= N)
            float m = -1.0e30f;
#pragma unroll
            for (int n = 0; n < NM; ++n) m = sv[n] > m ? sv[n] : m;
            float Z = 0.f;
#pragma unroll
            for (int n = 0; n < NM; ++n) Z += expf(sv[n] - m);
#pragma unroll
            for (int n = 0; n < NM; ++n) s_f[r * NM + ((n + r) & 63)] = expf(sv[n] - m) / Z;
        }
    }
    __syncthreads();

    // ================= Phase 3a: attn stores (coalesced) =================
#pragma unroll
    for (int it = 0; it < (RPB * NM) / NTHR; ++it) {   // 8 iters
        const int idx  = it * NTHR + t;
        const int r    = idx >> 6, n = idx & 63;       // r uniform per wave
        const int grow = row0 + r;
        if (grow < M) out_attn[(size_t)grow * NM + n] = s_f[r * NM + ((n + r) & 63)];
    }

    // ================= Phase 3b: retrieved (PV), float4 per lane =================
    // wave w rows [8w, 8w+8); lane l owns d-quad l (d = 4l..4l+3)
    {
        const float4* mem4 = reinterpret_cast<const float4*>(mem);   // [NM][64]
        const int kk = k < 16 ? k : 16;
#pragma unroll 1
        for (int rr = 0; rr < 8; ++rr) {
            const int r    = w * 8 + rr;
            const int grow = row0 + r;
            if (grow >= M) continue;
            float4 acc; acc.x = 0.f; acc.y = 0.f; acc.z = 0.f; acc.w = 0.f;
            if (k < NM) {
                for (int i = 0; i < kk; ++i) {
                    const int   mi = sel_i[r * 16 + i];
                    const float wz = sel_w[r * 16 + i];
                    const float4 mv = mem4[mi * 64 + l];       // coalesced 1KB
                    acc.x = fmaf(wz, mv.x, acc.x);             // rank-ascending chain
                    acc.y = fmaf(wz, mv.y, acc.y);
                    acc.z = fmaf(wz, mv.z, acc.z);
                    acc.w = fmaf(wz, mv.w, acc.w);
                }
            } else {
                for (int n = 0; n < NM; ++n) {
                    const float wz = s_f[r * NM + ((n + r) & 63)];
                    const float4 mv = mem4[n * 64 + l];
                    acc.x = fmaf(wz, mv.x, acc.x);             // n-ascending chain
                    acc.y = fmaf(wz, mv.y, acc.y);
                    acc.z = fmaf(wz, mv.z, acc.z);
                    acc.w = fmaf(wz, mv.w, acc.w);
                }
            }
            *reinterpret_cast<float4*>(&out_ret[(size_t)grow * DD + 4 * l]) = acc;
        }
    }
}

// ---------------------------------------------------------------------------
extern "C" void kernel_launch(void* const* d_in, const int* in_sizes, int n_in,
                              void* d_out, int out_size, void* d_ws, size_t ws_size,
                              hipStream_t stream) {
    const float* query      = (const float*)d_in[0];
    const float* memory     = (const float*)d_in[1];
    const float* importance = (const float*)d_in[2];
    const float* age        = (const float*)d_in[3];
    const float* Wq         = (const float*)d_in[4];
    const float* Wk         = (const float*)d_in[5];
    const int*   topk       = (const int*)d_in[6];

    const int M = in_sizes[0] / DD;   // B*S = 131072

    float* kT4  = (float*)d_ws;                      // [DD/4][NM][4] = 64 KB
    float* bias = kT4 + (size_t)DD * NM;             // [NM]
    float* wqt  = bias + 64;                         // [DD][DD] = 256 KB (16B aligned)
    float* wkt  = wqt + (size_t)DD * DD;             // [DD][DD] = 256 KB

    hipLaunchKernelGGL(prep_tr, dim3(DD, 2), dim3(DD), 0, stream,
                       Wq, Wk, wqt, wkt);
    hipLaunchKernelGGL(prep_kT, dim3(NM), dim3(DD), 0, stream,
                       memory, wkt, importance, age, kT4, bias);

    float* out_ret  = (float*)d_out;
    float* out_attn = out_ret + (size_t)M * DD;

    hipLaunchKernelGGL(mb_fused, dim3((M + RPB - 1) / RPB), dim3(NTHR), 0, stream,
                       query, memory,
                       (const float4*)wqt, (const float4*)kT4,
                       bias, topk, out_ret, out_attn, M);
}

// Round 13
// 501.090 us; speedup vs baseline: 1.5093x; 1.3437x over previous
//
#include <hip/hip_runtime.h>
#include <hip/hip_bf16.h>

#define DD 256      // feature dim
#define NM 64       // memory slots
#define RPB 64      // rows per block (main kernel)
#define NTHR 512    // 8 waves

typedef unsigned long long u64;

// ---------------------------------------------------------------------------
// prep_tr: wt[d][o] = W[o][d] for Wq and Wk (read-coalesced, scatter-write)
// ---------------------------------------------------------------------------
__global__ __launch_bounds__(256) void prep_tr(
    const float* __restrict__ Wq,    // [DD][DD]
    const float* __restrict__ Wk,    // [DD][DD]
    float* __restrict__ wqt,         // out [DD][DD]
    float* __restrict__ wkt)         // out [DD][DD]
{
    const int o = blockIdx.x;    // source row
    const int d = threadIdx.x;   // source col (coalesced read)
    if (blockIdx.y == 0) wqt[d * DD + o] = Wq[o * DD + d];
    else                 wkt[d * DD + o] = Wk[o * DD + d];
}

// ---------------------------------------------------------------------------
// prep_kT: kT4[(o>>2)*(NM*4) + n*4 + (o&3)] = k[n][o]
//          k[n][o] = sum_d mem[n][d]*Wk[o][d]  (fp32, d-ascending single-acc)
//          bias[n] = fl32(max(log(imp*0.99^age), -10))
// ---------------------------------------------------------------------------
__global__ __launch_bounds__(256) void prep_kT(
    const float* __restrict__ mem,   // [NM][DD]
    const float* __restrict__ wkt,   // [DD][DD]  (WkT: wkt[d][o])
    const float* __restrict__ imp,   // [NM]
    const float* __restrict__ age,   // [NM]
    float* __restrict__ kT4,         // out [DD/4][NM][4]
    float* __restrict__ bias)        // out [NM]
{
    const int n = blockIdx.x;   // memory slot
    const int o = threadIdx.x;  // output feature
    const float* mrow = mem + n * DD;     // uniform
    float acc = 0.f;
    for (int d = 0; d < DD; ++d)
        acc = fmaf(mrow[d], wkt[d * DD + o], acc);   // coalesced in o
    kT4[(o >> 2) * (NM * 4) + n * 4 + (o & 3)] = acc;

    if (o == 0) {
        double eff = (double)imp[n] * pow(0.99, (double)age[n]);
        float b = (float)log(eff);
        if (!(b >= -10.0f)) b = -10.0f;   // catches -inf/NaN too
        bias[n] = b;
    }
}

// ---------------------------------------------------------------------------
// fused main: 64 rows/block, 512 threads (8 waves), 64 KB LDS (2 blocks/CU).
// R13 key change: query comes off the SCALAR pipe. R7-R12 streamed query via
// s_load; SMEM returns out-of-order so every use forces lgkmcnt(0) draining
// ALL scalar loads -> un-hideable ~200cy/iter stall (VALUBusy pinned ~40%).
// Now: stage raw query rows into LDS (coalesced VMEM), Phase A reads them as
// uniform ds_read_b128 broadcasts (in-order lgkmcnt, prefetchable), wqt via
// rolling VMEM prefetch (in-order vmcnt). Zero in-loop s_loads.
// LDS alias: query-stage (64KB) -> overwritten by q after Phase A -> s/sel.
// All FMA chains bit-identical to R9/R12 (d-ascending / o-ascending / rank-
// ascending; same expressions).
// ---------------------------------------------------------------------------
__global__ __launch_bounds__(NTHR, 2) void mb_fused(
    const float* __restrict__ query,   // [M][DD]
    const float* __restrict__ mem,     // [NM][DD]
    const float4* __restrict__ wqt4,   // [DD][NM]: wqt4[d*64+l] = WqT[d][4l..4l+3]
    const float4* __restrict__ kT44,   // [DD/4][NM]: kT44[og*64+n] = k[n][4og..4og+3]
    const float* __restrict__ bias,    // [NM]
    const int* __restrict__ topk_p,
    float* __restrict__ out_ret,       // [M][DD]
    float* __restrict__ out_attn,      // [M][NM]
    int M)
{
    __shared__ float lds[RPB * DD];          // 64 KB: query-stage -> q -> s/sel
    float* s_f   = lds;                      //   s[64][64] (+r col rotation)
    int*   sel_i = (int*)(lds + RPB * NM);   //   [64][16]
    float* sel_w = lds + RPB * NM + RPB * 16;

    const int t = threadIdx.x;
    const int l = t & 63;
    const int w = __builtin_amdgcn_readfirstlane((int)(t >> 6));  // 0..7
    const int row0 = blockIdx.x * RPB;
    const int k = *topk_p;

    // ================= Stage: query rows -> LDS (coalesced VMEM) ==========
    {
        const float4* q4g = reinterpret_cast<const float4*>(query);
#pragma unroll
        for (int i = 0; i < (RPB * DD / 4) / NTHR; ++i) {   // 8 iters
            const int idx = i * NTHR + t;                   // 0..4095
            const int r   = idx >> 6;
            const int c4  = idx & 63;
            int gr = row0 + r; if (gr > M - 1) gr = M - 1;
            *reinterpret_cast<float4*>(&lds[r * DD + c4 * 4]) =
                q4g[(size_t)gr * 64 + c4];
        }
    }
    __syncthreads();

    // ================= Phase A: q-GEMM =================
    // wave w rows 8w..8w+7; lane l owns o = 4l..4l+3. query via uniform
    // ds_read broadcast; wqt via 1-deep rolling VMEM prefetch.
    float a0[8], a1[8], a2[8], a3[8];          // a{c}[rr]: o = 4l + c
    {
#pragma unroll
        for (int rr = 0; rr < 8; ++rr) { a0[rr] = 0.f; a1[rr] = 0.f; a2[rr] = 0.f; a3[rr] = 0.f; }

        // preload wqt tile for d0 = 0
        float4 cw0 = wqt4[0 * NM + l];
        float4 cw1 = wqt4[1 * NM + l];
        float4 cw2 = wqt4[2 * NM + l];
        float4 cw3 = wqt4[3 * NM + l];

        const float* qbase = &lds[(w * 8) * DD];   // wave's 8 query rows

        for (int d0 = 0; d0 < DD; d0 += 4) {
            const int dn = (d0 + 4) & (DD - 1);    // wraps on last iter
            const float4 nw0 = wqt4[(dn + 0) * NM + l];
            const float4 nw1 = wqt4[(dn + 1) * NM + l];
            const float4 nw2 = wqt4[(dn + 2) * NM + l];
            const float4 nw3 = wqt4[(dn + 3) * NM + l];
#pragma unroll
            for (int rr = 0; rr < 8; ++rr) {
                const float4 qq = *reinterpret_cast<const float4*>(
                    qbase + rr * DD + d0);         // uniform ds_read_b128 (broadcast)
                float v0 = a0[rr], v1 = a1[rr], v2 = a2[rr], v3 = a3[rr];
                // d-ascending per chain (identical to R12)
                v0 = fmaf(qq.x, cw0.x, v0); v0 = fmaf(qq.y, cw1.x, v0);
                v0 = fmaf(qq.z, cw2.x, v0); v0 = fmaf(qq.w, cw3.x, v0);
                v1 = fmaf(qq.x, cw0.y, v1); v1 = fmaf(qq.y, cw1.y, v1);
                v1 = fmaf(qq.z, cw2.y, v1); v1 = fmaf(qq.w, cw3.y, v1);
                v2 = fmaf(qq.x, cw0.z, v2); v2 = fmaf(qq.y, cw1.z, v2);
                v2 = fmaf(qq.z, cw2.z, v2); v2 = fmaf(qq.w, cw3.z, v2);
                v3 = fmaf(qq.x, cw0.w, v3); v3 = fmaf(qq.y, cw1.w, v3);
                v3 = fmaf(qq.z, cw2.w, v3); v3 = fmaf(qq.w, cw3.w, v3);
                a0[rr] = v0; a1[rr] = v1; a2[rr] = v2; a3[rr] = v3;
            }
            cw0 = nw0; cw1 = nw1; cw2 = nw2; cw3 = nw3;
        }
    }
    __syncthreads();   // all query reads done -> LDS reusable for q

    // ---- write q into LDS (swizzled: row lr, o-slot p stored at p^lr)
#pragma unroll
    for (int rr = 0; rr < 8; ++rr) {
        const int lr = w * 8 + rr;        // 0..63
        float4 v; v.x = a0[rr]; v.y = a1[rr]; v.z = a2[rr]; v.w = a3[rr];
        *reinterpret_cast<float4*>(&lds[lr * DD + (((l ^ lr) & 63) << 2)]) = v;
    }
    __syncthreads();

    // ================= Phase B: scores (registers only) =================
    // lane = row l; wave w owns n in [8w, 8w+8) -> kT addr wave-uniform (s_load)
    const int nb = w * 8;
    float sc[8];
    {
#pragma unroll
        for (int j = 0; j < 8; ++j) sc[j] = 0.f;

        for (int og = 0; og < DD / 4; ++og) {
            const float4 q4 = *reinterpret_cast<const float4*>(
                &lds[l * DD + (((og ^ l) & 63) << 2)]);       // 1 read / 64 rows
            const float4* ktp = kT44 + og * NM + nb;          // wave-uniform
#pragma unroll
            for (int j = 0; j < 8; ++j) {
                const float4 kt = ktp[j];
                float v = sc[j];
                v = fmaf(q4.x, kt.x, v);
                v = fmaf(q4.y, kt.y, v);
                v = fmaf(q4.z, kt.z, v);
                v = fmaf(q4.w, kt.w, v);
                sc[j] = v;
            }
        }
    }
    __syncthreads();    // all q reads done -> LDS reusable for s/sel

    // ---- write scores into aliased s_f[64][64] (col c stored at (c+row)&63)
#pragma unroll
    for (int j = 0; j < 8; ++j)
        s_f[l * NM + ((nb + j + l) & 63)] = sc[j] * 0.0625f + bias[nb + j];
    __syncthreads();

    // ================= Phase 2: per-row top-k (wave w, lanes 0..7) =========
    if (l < 8) {
        const int r = w * 8 + l;              // 0..63
        float sv[NM];
#pragma unroll
        for (int n = 0; n < NM; ++n) sv[n] = s_f[r * NM + ((n + r) & 63)];

        if (k < NM) {
            const int kk = k < 16 ? k : 16;   // dataset: k = 8
            u64 taken = 0ull;
            float mmax = 0.f, Z = 0.f;
            for (int i = 0; i < kk; ++i) {
                float m = -1.0e30f;
                int idx = 0;
#pragma unroll
                for (int n = 0; n < NM; ++n) {
                    const bool avail  = ((taken >> n) & 1ull) == 0ull;
                    const bool better = avail && (sv[n] > m);  // strict >: lowest idx ties
                    m   = better ? sv[n] : m;
                    idx = better ? n : idx;
                }
                taken |= (1ull << idx);
                if (i == 0) mmax = m;
                const float wv = expf(m - mmax);
                Z += wv;
                sel_i[r * 16 + i] = idx;
                sel_w[r * 16 + i] = wv;       // raw; divided once Z final
            }
#pragma unroll
            for (int n = 0; n < NM; ++n) s_f[r * NM + ((n + r) & 63)] = 0.f;
            for (int i = 0; i < kk; ++i) {
                const float wz = sel_w[r * 16 + i] / Z;
                sel_w[r * 16 + i] = wz;
                s_f[r * NM + ((sel_i[r * 16 + i] + r) & 63)] = wz;
            }
        } else {
            // full-softmax fallback (top_k >= N)
            float m = -1.0e30f;
#pragma unroll
            for (int n = 0; n < NM; ++n) m = sv[n] > m ? sv[n] : m;
            float Z = 0.f;
#pragma unroll
            for (int n = 0; n < NM; ++n) Z += expf(sv[n] - m);
#pragma unroll
            for (int n = 0; n < NM; ++n) s_f[r * NM + ((n + r) & 63)] = expf(sv[n] - m) / Z;
        }
    }
    __syncthreads();

    // ================= Phase 3a: attn stores (coalesced) =================
#pragma unroll
    for (int it = 0; it < (RPB * NM) / NTHR; ++it) {   // 8 iters
        const int idx  = it * NTHR + t;
        const int r    = idx >> 6, n = idx & 63;       // r uniform per wave
        const int grow = row0 + r;
        if (grow < M) out_attn[(size_t)grow * NM + n] = s_f[r * NM + ((n + r) & 63)];
    }

    // ================= Phase 3b: retrieved (PV), float4 per lane ===========
    // wave w rows [8w, 8w+8); lane l owns d-quad l (d = 4l..4l+3)
    {
        const float4* mem4 = reinterpret_cast<const float4*>(mem);   // [NM][64]
        const int kk = k < 16 ? k : 16;
#pragma unroll 1
        for (int rr = 0; rr < 8; ++rr) {
            const int r    = w * 8 + rr;
            const int grow = row0 + r;
            if (grow >= M) continue;
            float4 acc; acc.x = 0.f; acc.y = 0.f; acc.z = 0.f; acc.w = 0.f;
            if (k < NM) {
                for (int i = 0; i < kk; ++i) {
                    const int   mi = sel_i[r * 16 + i];
                    const float wz = sel_w[r * 16 + i];
                    const float4 mv = mem4[mi * 64 + l];       // coalesced 1KB
                    acc.x = fmaf(wz, mv.x, acc.x);             // rank-ascending chain
                    acc.y = fmaf(wz, mv.y, acc.y);
                    acc.z = fmaf(wz, mv.z, acc.z);
                    acc.w = fmaf(wz, mv.w, acc.w);
                }
            } else {
                for (int n = 0; n < NM; ++n) {
                    const float wz = s_f[r * NM + ((n + r) & 63)];
                    const float4 mv = mem4[n * 64 + l];
                    acc.x = fmaf(wz, mv.x, acc.x);             // n-ascending chain
                    acc.y = fmaf(wz, mv.y, acc.y);
                    acc.z = fmaf(wz, mv.z, acc.z);
                    acc.w = fmaf(wz, mv.w, acc.w);
                }
            }
            *reinterpret_cast<float4*>(&out_ret[(size_t)grow * DD + 4 * l]) = acc;
        }
    }
}

// ---------------------------------------------------------------------------
extern "C" void kernel_launch(void* const* d_in, const int* in_sizes, int n_in,
                              void* d_out, int out_size, void* d_ws, size_t ws_size,
                              hipStream_t stream) {
    const float* query      = (const float*)d_in[0];
    const float* memory     = (const float*)d_in[1];
    const float* importance = (const float*)d_in[2];
    const float* age        = (const float*)d_in[3];
    const float* Wq         = (const float*)d_in[4];
    const float* Wk         = (const float*)d_in[5];
    const int*   topk       = (const int*)d_in[6];

    const int M = in_sizes[0] / DD;   // B*S = 131072

    float* kT4  = (float*)d_ws;                      // [DD/4][NM][4] = 64 KB
    float* bias = kT4 + (size_t)DD * NM;             // [NM]
    float* wqt  = bias + 64;                         // [DD][DD] = 256 KB (16B aligned)
    float* wkt  = wqt + (size_t)DD * DD;             // [DD][DD] = 256 KB

    hipLaunchKernelGGL(prep_tr, dim3(DD, 2), dim3(DD), 0, stream,
                       Wq, Wk, wqt, wkt);
    hipLaunchKernelGGL(prep_kT, dim3(NM), dim3(DD), 0, stream,
                       memory, wkt, importance, age, kT4, bias);

    float* out_ret  = (float*)d_out;
    float* out_attn = out_ret + (size_t)M * DD;

    hipLaunchKernelGGL(mb_fused, dim3((M + RPB - 1) / RPB), dim3(NTHR), 0, stream,
                       query, memory,
                       (const float4*)wqt, (const float4*)kT4,
                       bias, topk, out_ret, out_attn, M);
}